// Round 5
// baseline (6199.576 us; speedup 1.0000x reference)
//
#include <hip/hip_runtime.h>
#include <math.h>

// ======================= compile-time real Clebsch-Gordan tables =======================

constexpr double FTAB[14]={1.0,1.0,2.0,6.0,24.0,120.0,720.0,5040.0,40320.0,362880.0,
                           3628800.0,39916800.0,479001600.0,6227020800.0};

constexpr double csqrt_(double x){
  if(x<=0.0) return 0.0;
  double g = x<1.0 ? 1.0 : x;
  for(int i=0;i<60;i++){
    double ng=0.5*(g+x/g);
    if(ng==g) break;
    g=ng;
  }
  return g;
}

constexpr double cgc_(int l1,int m1,int l2,int m2,int l3,int m3){
  if(m1+m2!=m3) return 0.0;
  int ad = l1>l2 ? l1-l2 : l2-l1;
  if(l3<ad || l3>l1+l2) return 0.0;
  double P=FTAB[l1+l2-l3]*FTAB[l1-l2+l3]*FTAB[-l1+l2+l3]/FTAB[l1+l2+l3+1]
          *FTAB[l1+m1]*FTAB[l1-m1]*FTAB[l2+m2]*FTAB[l2-m2]*FTAB[l3+m3]*FTAB[l3-m3];
  double spre=csqrt_(P);
  int kmin=0; if(l2-l3-m1>kmin)kmin=l2-l3-m1; if(l1-l3+m2>kmin)kmin=l1-l3+m2;
  int kmax=l1+l2-l3; if(l1-m1<kmax)kmax=l1-m1; if(l2+m2<kmax)kmax=l2+m2;
  double s=0.0;
  for(int k=kmin;k<=kmax;k++){
    double den=FTAB[k]*FTAB[l1+l2-l3-k]*FTAB[l1-m1-k]*FTAB[l2+m2-k]
              *FTAB[l3-l2+m1+k]*FTAB[l3-l1-m2+k];
    s+=((k&1)?-1.0:1.0)/den;
  }
  return csqrt_((double)(2*l3+1))*spre*s;
}

constexpr int lof_(int idx){ int l=0; while((l+1)*(l+1)<=idx) l++; return l; }

struct U2 { int c[2]; double re[2], im[2]; int n; };
constexpr U2 urow_(int idx){
  int l=lof_(idx);
  const double is2=0.70710678118654752440;
  U2 u{}; int off=l*l+l, m=idx-off;
  if(m==0){ u.c[0]=off; u.re[0]=1.0; u.im[0]=0.0; u.n=1; return u; }
  if(m>0){
    double sgn=(m&1)?-1.0:1.0;
    u.c[0]=off+m; u.re[0]=sgn*is2; u.im[0]=0.0;
    u.c[1]=off-m; u.re[1]=is2;     u.im[1]=0.0;
    u.n=2; return u;
  }
  int mm=-m; double sgn=(mm&1)?-1.0:1.0;
  u.c[0]=off-mm; u.re[0]=0.0; u.im[0]=is2;
  u.c[1]=off+mm; u.re[1]=0.0; u.im[1]=-sgn*is2;
  u.n=2; return u;
}

constexpr double realCG_(int i,int j,int k){
  int li=lof_(i), lj=lof_(j), lk=lof_(k);
  U2 ua=urow_(i), ub=urow_(j), uc=urow_(k);
  double Tre=0.0,Tim=0.0;
  for(int a=0;a<ua.n;a++)for(int b=0;b<ub.n;b++)for(int c=0;c<uc.n;c++){
    int ma=ua.c[a]-li*li-li, mb=ub.c[b]-lj*lj-lj, mc=uc.c[c]-lk*lk-lk;
    double cg=cgc_(li,ma,lj,mb,lk,mc);
    if(cg==0.0) continue;
    double xre=ua.re[a]*ub.re[b]-ua.im[a]*ub.im[b];
    double xim=ua.re[a]*ub.im[b]+ua.im[a]*ub.re[b];
    double wre=xre*uc.re[c]+xim*uc.im[c];
    double wim=xim*uc.re[c]-xre*uc.im[c];
    Tre+=wre*cg; Tim+=wim*cg;
  }
  double C=Tre+Tim;
  if(C<1e-12 && C>-1e-12) C=0.0;
  return C;
}

constexpr int path_l(int pi,int which){
  int idx=0;
  for(int l1=0;l1<=4;l1++)for(int l2=0;l2<=4;l2++){
    int lo = l1>l2 ? l1-l2 : l2-l1;
    int hi = (l1+l2<4)?(l1+l2):4;
    for(int l3=lo;l3<=hi;l3++){
      if(idx==pi) return which==0?l1:(which==1?l2:l3);
      idx++;
    }
  }
  return 0;
}

struct EntryList { int n; signed char ia[81]; signed char ib[81]; float v[81]; };

template<int L1,int L2,int L3,int C>
constexpr EntryList build_slot(){
  EntryList E{};
  for(int a=0;a<2*L1+1;a++)for(int b=0;b<2*L2+1;b++){
    double val=realCG_(L1*L1+a, L2*L2+b, L3*L3+C);
    if(val!=0.0){ E.ia[E.n]=(signed char)a; E.ib[E.n]=(signed char)b; E.v[E.n]=(float)val; E.n++; }
  }
  return E;
}
template<int L1,int L2,int L3,int C>
struct SlotTab { static constexpr EntryList E = build_slot<L1,L2,L3,C>(); };

template<int...I> struct iseq{};
template<int N,int...I> struct mkseq : mkseq<N-1,N-1,I...>{};
template<int...I> struct mkseq<0,I...>{ using type=iseq<I...>; };

// lane broadcast via v_readlane (uniform result, no LDS)
__device__ __forceinline__ float rl(float v,int k){
  return __int_as_float(__builtin_amdgcn_readlane(__float_as_int(v),k));
}

// final activation: v + v*tanh(softplus(v))
__device__ __forceinline__ float actv(float v){
  float sp=log1pf(expf(v));
  return v+v*tanhf(sp);
}

// ======================= register CG contraction, l3-major (tp0: single parity) ===========

template<int L3,int PI,int C>
__device__ __forceinline__ void t0_slot(const float(&a)[25],const float(&b)[25],
                                        float(&o0)[9],float(&o1)[9],float w00){
  constexpr int L1=path_l(PI,0),L2=path_l(PI,1);
  using ST=SlotTab<L1,L2,L3,C>;
  if constexpr(ST::E.n>0){
    float r=0.f;
    #pragma unroll
    for(int j=0;j<ST::E.n;j++)
      r += ST::E.v[j]*a[L1*L1+(int)ST::E.ia[j]]*b[L2*L2+(int)ST::E.ib[j]];
    constexpr int Sp=(L1+L2+L3)&1;
    if constexpr(Sp==0) o0[C]+=w00*r; else o1[C]+=w00*r;
  }
}
template<int L3,int PI,int...Cs>
__device__ __forceinline__ void t0_cs(iseq<Cs...>,const float(&a)[25],const float(&b)[25],
                                      float(&o0)[9],float(&o1)[9],float w00){
  (t0_slot<L3,PI,Cs>(a,b,o0,o1,w00), ...);
}
template<int L3,int PI>
__device__ __forceinline__ void t0_path(const float(&a)[25],const float(&b)[25],
                                        float(&o0)[9],float(&o1)[9],const float* __restrict__ wp,int f){
  if constexpr(path_l(PI,2)==L3){
    float w00=wp[PI*256+f];
    t0_cs<L3,PI>(typename mkseq<2*L3+1>::type{}, a,b,o0,o1,w00);
  }
}
// outputs to registers t0out[50] (p0 rows 0..24, p1 rows 25..49)
template<int L3,int...PIs>
__device__ __forceinline__ void t0_l3r(iseq<PIs...>,const float(&a)[25],const float(&b)[25],
                                       const float* __restrict__ wp,int f,float(&t0out)[50]){
  float o0[9],o1[9];
  #pragma unroll
  for(int c=0;c<9;c++){o0[c]=0.f;o1[c]=0.f;}
  (t0_path<L3,PIs>(a,b,o0,o1,wp,f), ...);
  #pragma unroll
  for(int c=0;c<2*L3+1;c++){
    t0out[L3*L3+c]    = o0[c];
    t0out[25+L3*L3+c] = o1[c];
  }
}

// ======================= register CG contraction, l3-major (tp1: two parities) ============

template<int L3,int PI,int C>
__device__ __forceinline__ void t1_slot(const float(&a0)[25],const float(&a1)[25],
                                        const float(&b0)[25],const float(&b1)[25],
                                        float(&o0)[9],float(&o1)[9],
                                        float w00,float w01,float w10,float w11){
  constexpr int L1=path_l(PI,0),L2=path_l(PI,1);
  using ST=SlotTab<L1,L2,L3,C>;
  if constexpr(ST::E.n>0){
    float r00=0.f,r01=0.f,r10=0.f,r11=0.f;
    #pragma unroll
    for(int j=0;j<ST::E.n;j++){
      float v=ST::E.v[j];
      float av0=a0[L1*L1+(int)ST::E.ia[j]], av1=a1[L1*L1+(int)ST::E.ia[j]];
      float bv0=b0[L2*L2+(int)ST::E.ib[j]], bv1=b1[L2*L2+(int)ST::E.ib[j]];
      float p=v*av0, q=v*av1;
      r00+=p*bv0; r01+=p*bv1; r10+=q*bv0; r11+=q*bv1;
    }
    constexpr int Sp=(L1+L2+L3)&1;
    float ev=w00*r00+w11*r11, od=w01*r01+w10*r10;
    if constexpr(Sp==0){ o0[C]+=ev; o1[C]+=od; }
    else               { o1[C]+=ev; o0[C]+=od; }
  }
}
template<int L3,int PI,int...Cs>
__device__ __forceinline__ void t1_cs(iseq<Cs...>,const float(&a0)[25],const float(&a1)[25],
                                      const float(&b0)[25],const float(&b1)[25],
                                      float(&o0)[9],float(&o1)[9],
                                      float w00,float w01,float w10,float w11){
  (t1_slot<L3,PI,Cs>(a0,a1,b0,b1,o0,o1,w00,w01,w10,w11), ...);
}
template<int L3,int PI>
__device__ __forceinline__ void t1_path(const float(&a0)[25],const float(&a1)[25],
                                        const float(&b0)[25],const float(&b1)[25],
                                        float(&o0)[9],float(&o1)[9],const float* __restrict__ wp,int f){
  if constexpr(path_l(PI,2)==L3){
    const float* wpp=wp+PI*256+f;
    float w00=wpp[0], w01=wpp[64], w10=wpp[128], w11=wpp[192];
    t1_cs<L3,PI>(typename mkseq<2*L3+1>::type{}, a0,a1,b0,b1,o0,o1,w00,w01,w10,w11);
  }
}
// fused epilogue: activation + store of ch 80..143 (DEGLM[lm]==L3 inside the block)
template<int L3,int...PIs>
__device__ __forceinline__ void t1_l3w(iseq<PIs...>,const float(&a0)[25],const float(&a1)[25],
                                       const float(&b0)[25],const float(&b1)[25],
                                       const float* __restrict__ wp,int f,
                                       float* __restrict__ ybase,
                                       const float* __restrict__ wf,float te2){
  float o0[9],o1[9];
  #pragma unroll
  for(int c=0;c<9;c++){o0[c]=0.f;o1[c]=0.f;}
  (t1_path<L3,PIs>(a0,a1,b0,b1,o0,o1,wp,f), ...);
  float w0v=wf[L3*144+80+f];        // p=0: (0*5+L3)
  float w1v=wf[(5+L3)*144+80+f];    // p=1
  #pragma unroll
  for(int c=0;c<2*L3+1;c++){
    int lm=L3*L3+c;
    float v0=te2*o0[c]*w0v;
    if(L3==0&&c==0) v0+=te2;        // global row 0 (p0,lm0) += te
    v0=actv(v0);
    ybase[lm*144+80+f]=v0;
    float v1=te2*o1[c]*w1v;
    v1=actv(v1);
    ybase[(25+lm)*144+80+f]=v1;
  }
}

// ======================= init =======================

__global__ __launch_bounds__(256) void k_zero(int* cnt, int N){
  int t=blockIdx.x*256+threadIdx.x; if(t<N) cnt[t]=0;
}

// ======================= edge stage =======================

__global__ __launch_bounds__(256) void k_edge(const int* __restrict__ Z, const int* __restrict__ nbr,
    const float* __restrict__ disp, const float* __restrict__ Wsp,
    float* __restrict__ g, float* __restrict__ Ye, int* cnt, int E){
  int e=blockIdx.x*256+threadIdx.x; if(e>=E) return;
  int i0=nbr[2*e], j0=nbr[2*e+1];
  atomicAdd(&cnt[i0],1);
  int z=Z[j0];
  float dx=disp[3*e], dy=disp[3*e+1], dz=disp[3*e+2];
  float r=sqrtf(dx*dx+dy*dy+dz*dz+1e-12f);
  float inv=1.0f/r;
  float x=dx*inv, y=dy*inv, zz=dz*inv;
  float rc=fminf(r*0.2f,1.0f);
  float fc=0.5f*(cosf(3.14159265358979323846f*rc)+1.0f);
  float rbf[16];
  #pragma unroll
  for(int k=0;k<16;k++){
    float d=r-(float)k*(5.0f/15.0f);
    rbf[k]=expf(-10.24f*d*d)*fc;
  }
  const float* Wz=Wsp + z*256;
  #pragma unroll
  for(int rr=0;rr<16;rr++){
    float s=0.f;
    #pragma unroll
    for(int k=0;k<16;k++) s += rbf[k]*Wz[k*16+rr];
    g[e*16+rr]=s;
  }
  float x2=x*x,y2=y*y,z2=zz*zz;
  float* Y=Ye+(size_t)e*25;
  Y[0]=0.28209479177387814f;
  Y[1]=0.4886025119029199f*y;
  Y[2]=0.4886025119029199f*zz;
  Y[3]=0.4886025119029199f*x;
  Y[4]=1.0925484305920792f*x*y;
  Y[5]=1.0925484305920792f*y*zz;
  Y[6]=0.31539156525252005f*(3.f*z2-1.f);
  Y[7]=1.0925484305920792f*x*zz;
  Y[8]=0.5462742152960396f*(x2-y2);
  Y[9]=0.5900435899266435f*y*(3.f*x2-y2);
  Y[10]=2.890611442640554f*x*y*zz;
  Y[11]=0.4570457994644658f*y*(5.f*z2-1.f);
  Y[12]=0.3731763325901154f*zz*(5.f*z2-3.f);
  Y[13]=0.4570457994644658f*x*(5.f*z2-1.f);
  Y[14]=1.445305721320277f*zz*(x2-y2);
  Y[15]=0.5900435899266435f*x*(x2-3.f*y2);
  Y[16]=2.5033429417967046f*x*y*(x2-y2);
  Y[17]=1.7701307697799304f*y*zz*(3.f*x2-y2);
  Y[18]=0.9461746957575601f*x*y*(7.f*z2-1.f);
  Y[19]=0.6690465435572892f*y*zz*(7.f*z2-3.f);
  Y[20]=0.10578554691520431f*(35.f*z2*z2-30.f*z2+3.f);
  Y[21]=0.6690465435572892f*x*zz*(7.f*z2-3.f);
  Y[22]=0.47308734787878004f*(x2-y2)*(7.f*z2-1.f);
  Y[23]=1.7701307697799304f*x*zz*(x2-3.f*y2);
  Y[24]=0.6258357354491761f*(x2*x2-6.f*x2*y2+y2*y2);
}

// ======================= CSR build =======================

__global__ __launch_bounds__(1024) void k_scan(const int* __restrict__ cnt, int* offs, int* cursor, int N){
  __shared__ int part[1024];
  int t=threadIdx.x;
  int per=(N+1023)>>10;
  int start=t*per;
  int s=0;
  for(int i2=0;i2<per;i2++){int idx=start+i2; if(idx<N) s+=cnt[idx];}
  part[t]=s; __syncthreads();
  for(int off=1;off<1024;off<<=1){
    int v=(t>=off)?part[t-off]:0;
    __syncthreads();
    part[t]+=v;
    __syncthreads();
  }
  int run=(t>0)?part[t-1]:0;
  for(int i2=0;i2<per;i2++){int idx=start+i2; if(idx<N){offs[idx]=run; cursor[idx]=run; run+=cnt[idx];}}
  if(t==1023) offs[N]=part[1023];
}

__global__ __launch_bounds__(256) void k_fill(const int* __restrict__ nbr, int* cursor, int* elist, int E){
  int e=blockIdx.x*256+threadIdx.x; if(e>=E)return;
  int pos=atomicAdd(&cursor[nbr[2*e]],1);
  elist[pos]=e;
}

// ======================= aggregation: y0 -> d_out ch 0..15 (p0 rows only) ==================

__global__ __launch_bounds__(64) void k_agg(const float* __restrict__ g, const float* __restrict__ Ye,
    const int* __restrict__ offs, const int* __restrict__ elist, const float* __restrict__ norm,
    float* __restrict__ y){
  int n=blockIdx.x, t=threadIdx.x;
  __shared__ float gs[16];
  __shared__ float ys[25];
  float acc[7];
  #pragma unroll
  for(int i2=0;i2<7;i2++) acc[i2]=0.f;
  int e0=offs[n], e1=offs[n+1];
  for(int ei=e0; ei<e1; ei++){
    int e=elist[ei];
    if(t<16) gs[t]=g[(size_t)e*16+t];
    else if(t<41) ys[t-16]=Ye[(size_t)e*25+t-16];
    __syncthreads();
    #pragma unroll
    for(int i2=0;i2<7;i2++){
      int o=t+64*i2;
      if(o<400) acc[i2] += ys[o>>4]*gs[o&15];
    }
    __syncthreads();
  }
  float nv=1.0f/norm[0];
  float* yo=y+(size_t)n*7200;
  #pragma unroll
  for(int i2=0;i2<7;i2++){
    int o=t+64*i2;
    if(o<400){ int lm=o>>4,k=o&15; yo[lm*144+k]=acc[i2]*nv; }
  }
}

// ======================= te precompute: te[n][c] = emb[Z[n]] @ Wet + bet ==================

__global__ __launch_bounds__(128) void k_te(const int* __restrict__ Z, const float* __restrict__ emb,
    const float* __restrict__ Wet, const float* __restrict__ bet, float* __restrict__ te){
  int n=blockIdx.x, t=threadIdx.x;
  __shared__ float embs[64];
  int z=Z[n];
  if(t<64) embs[t]=emb[z*64+t];
  __syncthreads();
  for(int c=t;c<144;c+=128){
    float s=bet[c];
    for(int d=0;d<64;d++) s+=embs[d]*Wet[d*144+c];
    te[(size_t)n*144+c]=s;
  }
}

// ======================= fused TP0 + TP1 + final — 1 wave/atom, all-register ==============

__global__ __launch_bounds__(64) __attribute__((amdgpu_waves_per_eu(1,2)))
void k_tp(float* __restrict__ y,
          const float* __restrict__ W1_0, const float* __restrict__ W2_0, const float* __restrict__ wp0,
          const float* __restrict__ W1_1, const float* __restrict__ W2_1, const float* __restrict__ wp1,
          const float* __restrict__ te, const float* __restrict__ wf){
  int n=blockIdx.x, f=threadIdx.x;
  float* ybase = y + (size_t)n*7200;

  // ---- load y0 (p0 rows, ch 0..15): lane f holds ch (f&15), 4-way replicated ----
  float y0r[25];
  #pragma unroll
  for(int lm=0;lm<25;lm++) y0r[lm]=ybase[lm*144+(f&15)];

  // ---- tp0 degree-dense (K=16) ----
  float a[25],b[25];
  #pragma unroll
  for(int i=0;i<25;i++){a[i]=0.f;b[i]=0.f;}
  #pragma unroll
  for(int l=0;l<5;l++){
    const int n1=2*l+1, base=l*l;
    const float* w1=W1_0+l*1024+f;
    const float* w2=W2_0+l*1024+f;
    #pragma unroll 8
    for(int k=0;k<16;k++){
      float u1=w1[k*64], u2=w2[k*64];
      #pragma unroll
      for(int j=0;j<n1;j++){
        float yv=rl(y0r[base+j],k);
        a[base+j]+=yv*u1; b[base+j]+=yv*u2;
      }
    }
  }

  // ---- final activation + store for ch 0..15 (frees y0r) ----
  {
    float te0=te[(size_t)n*144+(f&15)];
    #pragma unroll
    for(int lm=0;lm<25;lm++){
      float wv=wf[lof_(lm)*144+(f&15)];    // p=0 block
      float v=te0*y0r[lm]*wv;
      if(lm==0) v+=te0;
      v=actv(v);
      if(f<16){
        ybase[lm*144+f]=v;                 // p0 rows: activated y0
        ybase[(25+lm)*144+f]=0.f;          // p1 rows: act(0)=0
      }
    }
  }

  // ---- tp0 CG -> t0out[50] in registers ----
  float t0out[50];
  t0_l3r<0>(typename mkseq<65>::type{}, a,b,wp0,f,t0out);
  t0_l3r<1>(typename mkseq<65>::type{}, a,b,wp0,f,t0out);
  t0_l3r<2>(typename mkseq<65>::type{}, a,b,wp0,f,t0out);
  t0_l3r<3>(typename mkseq<65>::type{}, a,b,wp0,f,t0out);
  t0_l3r<4>(typename mkseq<65>::type{}, a,b,wp0,f,t0out);

  // ---- tp1 degree-dense (K=64) over t0out ----
  float a0[25],a1[25],b0[25],b1[25];
  #pragma unroll
  for(int i=0;i<25;i++){a0[i]=0.f;a1[i]=0.f;b0[i]=0.f;b1[i]=0.f;}
  #pragma unroll
  for(int p=0;p<2;p++){
    #pragma unroll
    for(int l=0;l<5;l++){
      const int n1=2*l+1, base=l*l;
      const float* w1=W1_1+(p*5+l)*4096+f;
      const float* w2=W2_1+(p*5+l)*4096+f;
      #pragma unroll 8
      for(int k=0;k<64;k++){
        float u1=w1[k*64], u2=w2[k*64];
        #pragma unroll
        for(int j=0;j<n1;j++){
          float yv=rl(t0out[p*25+base+j],k);
          if(p==0){ a0[base+j]+=yv*u1; b0[base+j]+=yv*u2; }
          else    { a1[base+j]+=yv*u1; b1[base+j]+=yv*u2; }
        }
      }
    }
  }

  // ---- final activation + store for ch 16..79 (frees t0out) ----
  {
    float te1=te[(size_t)n*144+16+f];
    #pragma unroll
    for(int p=0;p<2;p++){
      #pragma unroll
      for(int l=0;l<5;l++){
        float wv=wf[(p*5+l)*144+16+f];
        #pragma unroll
        for(int j=0;j<2*l+1;j++){
          int row=p*25+l*l+j;
          float v=te1*t0out[row]*wv;
          if(p==0&&l==0&&j==0) v+=te1;
          v=actv(v);
          ybase[row*144+16+f]=v;
        }
      }
    }
  }

  // ---- tp1 CG + final activation + store for ch 80..143, per l3 ----
  {
    float te2=te[(size_t)n*144+80+f];
    t1_l3w<0>(typename mkseq<65>::type{}, a0,a1,b0,b1,wp1,f,ybase,wf,te2);
    t1_l3w<1>(typename mkseq<65>::type{}, a0,a1,b0,b1,wp1,f,ybase,wf,te2);
    t1_l3w<2>(typename mkseq<65>::type{}, a0,a1,b0,b1,wp1,f,ybase,wf,te2);
    t1_l3w<3>(typename mkseq<65>::type{}, a0,a1,b0,b1,wp1,f,ybase,wf,te2);
    t1_l3w<4>(typename mkseq<65>::type{}, a0,a1,b0,b1,wp1,f,ybase,wf,te2);
  }
}

// ======================= launch =======================

extern "C" void kernel_launch(void* const* d_in, const int* in_sizes, int n_in,
                              void* d_out, int out_size, void* d_ws, size_t ws_size,
                              hipStream_t stream) {
  const int*   Z    =(const int*)  d_in[0];
  const int*   nbr  =(const int*)  d_in[1];
  const float* disp =(const float*)d_in[2];
  const float* Wsp  =(const float*)d_in[3];
  const float* emb  =(const float*)d_in[4];
  const float* Wet  =(const float*)d_in[5];
  const float* bet  =(const float*)d_in[6];
  const float* norm =(const float*)d_in[7];
  const float* t0W1 =(const float*)d_in[8];
  const float* t0W2 =(const float*)d_in[9];
  const float* t0wp =(const float*)d_in[10];
  const float* t1W1 =(const float*)d_in[11];
  const float* t1W2 =(const float*)d_in[12];
  const float* t1wp =(const float*)d_in[13];
  const float* wf   =(const float*)d_in[14];
  int N=in_sizes[0];
  int E=in_sizes[1]/2;
  float* y=(float*)d_out;

  char* w=(char*)d_ws;
  size_t off=0;
  auto take=[&](size_t bytes)->void*{ size_t cur=(off+255)&~(size_t)255; off=cur+bytes; return (void*)(w+cur); };
  int*   cnt   =(int*)  take((size_t)N*4);
  int*   offs  =(int*)  take((size_t)(N+1)*4);
  int*   cursor=(int*)  take((size_t)N*4);
  int*   elist =(int*)  take((size_t)E*4);
  float* g     =(float*)take((size_t)E*16*4);
  float* Ye    =(float*)take((size_t)E*25*4);
  float* te    =(float*)take((size_t)N*144*4);
  (void)ws_size; (void)out_size; (void)n_in;

  k_zero   <<<dim3((N+255)/256),   dim3(256), 0, stream>>>(cnt, N);
  k_edge   <<<dim3((E+255)/256),   dim3(256), 0, stream>>>(Z, nbr, disp, Wsp, g, Ye, cnt, E);
  k_scan   <<<dim3(1),             dim3(1024),0, stream>>>(cnt, offs, cursor, N);
  k_fill   <<<dim3((E+255)/256),   dim3(256), 0, stream>>>(nbr, cursor, elist, E);
  k_agg    <<<dim3(N),             dim3(64),  0, stream>>>(g, Ye, offs, elist, norm, y);
  k_te     <<<dim3(N),             dim3(128), 0, stream>>>(Z, emb, Wet, bet, te);
  k_tp     <<<dim3(N),             dim3(64),  0, stream>>>(y, t0W1, t0W2, t0wp, t1W1, t1W2, t1wp, te, wf);
}

// Round 6
// 2163.913 us; speedup vs baseline: 2.8650x; 2.8650x over previous
//
#include <hip/hip_runtime.h>
#include <math.h>

// ======================= compile-time real Clebsch-Gordan tables =======================

constexpr double FTAB[14]={1.0,1.0,2.0,6.0,24.0,120.0,720.0,5040.0,40320.0,362880.0,
                           3628800.0,39916800.0,479001600.0,6227020800.0};

constexpr double csqrt_(double x){
  if(x<=0.0) return 0.0;
  double g = x<1.0 ? 1.0 : x;
  for(int i=0;i<60;i++){
    double ng=0.5*(g+x/g);
    if(ng==g) break;
    g=ng;
  }
  return g;
}

constexpr double cgc_(int l1,int m1,int l2,int m2,int l3,int m3){
  if(m1+m2!=m3) return 0.0;
  int ad = l1>l2 ? l1-l2 : l2-l1;
  if(l3<ad || l3>l1+l2) return 0.0;
  double P=FTAB[l1+l2-l3]*FTAB[l1-l2+l3]*FTAB[-l1+l2+l3]/FTAB[l1+l2+l3+1]
          *FTAB[l1+m1]*FTAB[l1-m1]*FTAB[l2+m2]*FTAB[l2-m2]*FTAB[l3+m3]*FTAB[l3-m3];
  double spre=csqrt_(P);
  int kmin=0; if(l2-l3-m1>kmin)kmin=l2-l3-m1; if(l1-l3+m2>kmin)kmin=l1-l3+m2;
  int kmax=l1+l2-l3; if(l1-m1<kmax)kmax=l1-m1; if(l2+m2<kmax)kmax=l2+m2;
  double s=0.0;
  for(int k=kmin;k<=kmax;k++){
    double den=FTAB[k]*FTAB[l1+l2-l3-k]*FTAB[l1-m1-k]*FTAB[l2+m2-k]
              *FTAB[l3-l2+m1+k]*FTAB[l3-l1-m2+k];
    s+=((k&1)?-1.0:1.0)/den;
  }
  return csqrt_((double)(2*l3+1))*spre*s;
}

constexpr int lof_(int idx){ int l=0; while((l+1)*(l+1)<=idx) l++; return l; }

struct U2 { int c[2]; double re[2], im[2]; int n; };
constexpr U2 urow_(int idx){
  int l=lof_(idx);
  const double is2=0.70710678118654752440;
  U2 u{}; int off=l*l+l, m=idx-off;
  if(m==0){ u.c[0]=off; u.re[0]=1.0; u.im[0]=0.0; u.n=1; return u; }
  if(m>0){
    double sgn=(m&1)?-1.0:1.0;
    u.c[0]=off+m; u.re[0]=sgn*is2; u.im[0]=0.0;
    u.c[1]=off-m; u.re[1]=is2;     u.im[1]=0.0;
    u.n=2; return u;
  }
  int mm=-m; double sgn=(mm&1)?-1.0:1.0;
  u.c[0]=off-mm; u.re[0]=0.0; u.im[0]=is2;
  u.c[1]=off+mm; u.re[1]=0.0; u.im[1]=-sgn*is2;
  u.n=2; return u;
}

constexpr double realCG_(int i,int j,int k){
  int li=lof_(i), lj=lof_(j), lk=lof_(k);
  U2 ua=urow_(i), ub=urow_(j), uc=urow_(k);
  double Tre=0.0,Tim=0.0;
  for(int a=0;a<ua.n;a++)for(int b=0;b<ub.n;b++)for(int c=0;c<uc.n;c++){
    int ma=ua.c[a]-li*li-li, mb=ub.c[b]-lj*lj-lj, mc=uc.c[c]-lk*lk-lk;
    double cg=cgc_(li,ma,lj,mb,lk,mc);
    if(cg==0.0) continue;
    double xre=ua.re[a]*ub.re[b]-ua.im[a]*ub.im[b];
    double xim=ua.re[a]*ub.im[b]+ua.im[a]*ub.re[b];
    double wre=xre*uc.re[c]+xim*uc.im[c];
    double wim=xim*uc.re[c]-xre*uc.im[c];
    Tre+=wre*cg; Tim+=wim*cg;
  }
  double C=Tre+Tim;
  if(C<1e-12 && C>-1e-12) C=0.0;
  return C;
}

constexpr int path_l(int pi,int which){
  int idx=0;
  for(int l1=0;l1<=4;l1++)for(int l2=0;l2<=4;l2++){
    int lo = l1>l2 ? l1-l2 : l2-l1;
    int hi = (l1+l2<4)?(l1+l2):4;
    for(int l3=lo;l3<=hi;l3++){
      if(idx==pi) return which==0?l1:(which==1?l2:l3);
      idx++;
    }
  }
  return 0;
}

struct EntryList { int n; signed char ia[81]; signed char ib[81]; float v[81]; };

template<int L1,int L2,int L3,int C>
constexpr EntryList build_slot(){
  EntryList E{};
  for(int a=0;a<2*L1+1;a++)for(int b=0;b<2*L2+1;b++){
    double val=realCG_(L1*L1+a, L2*L2+b, L3*L3+C);
    if(val!=0.0){ E.ia[E.n]=(signed char)a; E.ib[E.n]=(signed char)b; E.v[E.n]=(float)val; E.n++; }
  }
  return E;
}
template<int L1,int L2,int L3,int C>
struct SlotTab { static constexpr EntryList E = build_slot<L1,L2,L3,C>(); };

template<int...I> struct iseq{};
template<int N,int...I> struct mkseq : mkseq<N-1,N-1,I...>{};
template<int...I> struct mkseq<0,I...>{ using type=iseq<I...>; };

// lane broadcast via v_readlane (uniform result, no LDS)
__device__ __forceinline__ float rl(float v,int k){
  return __int_as_float(__builtin_amdgcn_readlane(__float_as_int(v),k));
}

// final activation: v + v*tanh(softplus(v))
__device__ __forceinline__ float actv(float v){
  float sp=log1pf(expf(v));
  return v+v*tanhf(sp);
}

// ======================= register CG contraction, l3-major (tp0: single parity) ===========

template<int L3,int PI,int C>
__device__ __forceinline__ void t0_slot(const float(&a)[25],const float(&b)[25],
                                        float(&o0)[9],float(&o1)[9],float w00){
  constexpr int L1=path_l(PI,0),L2=path_l(PI,1);
  using ST=SlotTab<L1,L2,L3,C>;
  if constexpr(ST::E.n>0){
    float r=0.f;
    #pragma unroll
    for(int j=0;j<ST::E.n;j++)
      r += ST::E.v[j]*a[L1*L1+(int)ST::E.ia[j]]*b[L2*L2+(int)ST::E.ib[j]];
    constexpr int Sp=(L1+L2+L3)&1;
    if constexpr(Sp==0) o0[C]+=w00*r; else o1[C]+=w00*r;
  }
}
template<int L3,int PI,int...Cs>
__device__ __forceinline__ void t0_cs(iseq<Cs...>,const float(&a)[25],const float(&b)[25],
                                      float(&o0)[9],float(&o1)[9],float w00){
  (t0_slot<L3,PI,Cs>(a,b,o0,o1,w00), ...);
}
template<int L3,int PI>
__device__ __forceinline__ void t0_path(const float(&a)[25],const float(&b)[25],
                                        float(&o0)[9],float(&o1)[9],const float* __restrict__ wp,int f){
  if constexpr(path_l(PI,2)==L3){
    float w00=wp[PI*256+f];
    t0_cs<L3,PI>(typename mkseq<2*L3+1>::type{}, a,b,o0,o1,w00);
  }
}
// direct RAW store of tp0 CG output to ch16..79 (lane f -> ch 16+f)
template<int L3,int...PIs>
__device__ __forceinline__ void t0_l3(iseq<PIs...>,const float(&a)[25],const float(&b)[25],
                                      const float* __restrict__ wp,int f,float* __restrict__ yo){
  float o0[9],o1[9];
  #pragma unroll
  for(int c=0;c<9;c++){o0[c]=0.f;o1[c]=0.f;}
  (t0_path<L3,PIs>(a,b,o0,o1,wp,f), ...);
  #pragma unroll
  for(int c=0;c<2*L3+1;c++){
    yo[(L3*L3+c)*144+f]      = o0[c];
    yo[3600+(L3*L3+c)*144+f] = o1[c];
  }
}

// ======================= register CG contraction, l3-major (tp1: two parities) ============

template<int L3,int PI,int C>
__device__ __forceinline__ void t1_slot(const float(&a0)[25],const float(&a1)[25],
                                        const float(&b0)[25],const float(&b1)[25],
                                        float(&o0)[9],float(&o1)[9],
                                        float w00,float w01,float w10,float w11){
  constexpr int L1=path_l(PI,0),L2=path_l(PI,1);
  using ST=SlotTab<L1,L2,L3,C>;
  if constexpr(ST::E.n>0){
    float r00=0.f,r01=0.f,r10=0.f,r11=0.f;
    #pragma unroll
    for(int j=0;j<ST::E.n;j++){
      float v=ST::E.v[j];
      float av0=a0[L1*L1+(int)ST::E.ia[j]], av1=a1[L1*L1+(int)ST::E.ia[j]];
      float bv0=b0[L2*L2+(int)ST::E.ib[j]], bv1=b1[L2*L2+(int)ST::E.ib[j]];
      float p=v*av0, q=v*av1;
      r00+=p*bv0; r01+=p*bv1; r10+=q*bv0; r11+=q*bv1;
    }
    constexpr int Sp=(L1+L2+L3)&1;
    float ev=w00*r00+w11*r11, od=w01*r01+w10*r10;
    if constexpr(Sp==0){ o0[C]+=ev; o1[C]+=od; }
    else               { o1[C]+=ev; o0[C]+=od; }
  }
}
template<int L3,int PI,int...Cs>
__device__ __forceinline__ void t1_cs(iseq<Cs...>,const float(&a0)[25],const float(&a1)[25],
                                      const float(&b0)[25],const float(&b1)[25],
                                      float(&o0)[9],float(&o1)[9],
                                      float w00,float w01,float w10,float w11){
  (t1_slot<L3,PI,Cs>(a0,a1,b0,b1,o0,o1,w00,w01,w10,w11), ...);
}
template<int L3,int PI>
__device__ __forceinline__ void t1_path(const float(&a0)[25],const float(&a1)[25],
                                        const float(&b0)[25],const float(&b1)[25],
                                        float(&o0)[9],float(&o1)[9],const float* __restrict__ wp,int f){
  if constexpr(path_l(PI,2)==L3){
    const float* wpp=wp+PI*256+f;
    float w00=wpp[0], w01=wpp[64], w10=wpp[128], w11=wpp[192];
    t1_cs<L3,PI>(typename mkseq<2*L3+1>::type{}, a0,a1,b0,b1,o0,o1,w00,w01,w10,w11);
  }
}
// fused epilogue: activation + store of ch 80..143 (lane f -> ch 80+f)
template<int L3,int...PIs>
__device__ __forceinline__ void t1_l3w(iseq<PIs...>,const float(&a0)[25],const float(&a1)[25],
                                       const float(&b0)[25],const float(&b1)[25],
                                       const float* __restrict__ wp,int f,
                                       float* __restrict__ ybase,
                                       const float* __restrict__ wf,float te2){
  float o0[9],o1[9];
  #pragma unroll
  for(int c=0;c<9;c++){o0[c]=0.f;o1[c]=0.f;}
  (t1_path<L3,PIs>(a0,a1,b0,b1,o0,o1,wp,f), ...);
  float w0v=wf[L3*144+80+f];        // p=0: (0*5+L3)
  float w1v=wf[(5+L3)*144+80+f];    // p=1
  #pragma unroll
  for(int c=0;c<2*L3+1;c++){
    int lm=L3*L3+c;
    float v0=te2*o0[c]*w0v;
    if(L3==0&&c==0) v0+=te2;        // global row 0 (p0,lm0) += te
    v0=actv(v0);
    ybase[lm*144+80+f]=v0;
    float v1=te2*o1[c]*w1v;
    v1=actv(v1);
    ybase[(25+lm)*144+80+f]=v1;
  }
}

// ======================= init =======================

__global__ __launch_bounds__(256) void k_zero(int* cnt, int N){
  int t=blockIdx.x*256+threadIdx.x; if(t<N) cnt[t]=0;
}

// ======================= edge stage =======================

__global__ __launch_bounds__(256) void k_edge(const int* __restrict__ Z, const int* __restrict__ nbr,
    const float* __restrict__ disp, const float* __restrict__ Wsp,
    float* __restrict__ g, float* __restrict__ Ye, int* cnt, int E){
  int e=blockIdx.x*256+threadIdx.x; if(e>=E) return;
  int i0=nbr[2*e], j0=nbr[2*e+1];
  atomicAdd(&cnt[i0],1);
  int z=Z[j0];
  float dx=disp[3*e], dy=disp[3*e+1], dz=disp[3*e+2];
  float r=sqrtf(dx*dx+dy*dy+dz*dz+1e-12f);
  float inv=1.0f/r;
  float x=dx*inv, y=dy*inv, zz=dz*inv;
  float rc=fminf(r*0.2f,1.0f);
  float fc=0.5f*(cosf(3.14159265358979323846f*rc)+1.0f);
  float rbf[16];
  #pragma unroll
  for(int k=0;k<16;k++){
    float d=r-(float)k*(5.0f/15.0f);
    rbf[k]=expf(-10.24f*d*d)*fc;
  }
  const float* Wz=Wsp + z*256;
  #pragma unroll
  for(int rr=0;rr<16;rr++){
    float s=0.f;
    #pragma unroll
    for(int k=0;k<16;k++) s += rbf[k]*Wz[k*16+rr];
    g[e*16+rr]=s;
  }
  float x2=x*x,y2=y*y,z2=zz*zz;
  float* Y=Ye+(size_t)e*25;
  Y[0]=0.28209479177387814f;
  Y[1]=0.4886025119029199f*y;
  Y[2]=0.4886025119029199f*zz;
  Y[3]=0.4886025119029199f*x;
  Y[4]=1.0925484305920792f*x*y;
  Y[5]=1.0925484305920792f*y*zz;
  Y[6]=0.31539156525252005f*(3.f*z2-1.f);
  Y[7]=1.0925484305920792f*x*zz;
  Y[8]=0.5462742152960396f*(x2-y2);
  Y[9]=0.5900435899266435f*y*(3.f*x2-y2);
  Y[10]=2.890611442640554f*x*y*zz;
  Y[11]=0.4570457994644658f*y*(5.f*z2-1.f);
  Y[12]=0.3731763325901154f*zz*(5.f*z2-3.f);
  Y[13]=0.4570457994644658f*x*(5.f*z2-1.f);
  Y[14]=1.445305721320277f*zz*(x2-y2);
  Y[15]=0.5900435899266435f*x*(x2-3.f*y2);
  Y[16]=2.5033429417967046f*x*y*(x2-y2);
  Y[17]=1.7701307697799304f*y*zz*(3.f*x2-y2);
  Y[18]=0.9461746957575601f*x*y*(7.f*z2-1.f);
  Y[19]=0.6690465435572892f*y*zz*(7.f*z2-3.f);
  Y[20]=0.10578554691520431f*(35.f*z2*z2-30.f*z2+3.f);
  Y[21]=0.6690465435572892f*x*zz*(7.f*z2-3.f);
  Y[22]=0.47308734787878004f*(x2-y2)*(7.f*z2-1.f);
  Y[23]=1.7701307697799304f*x*zz*(x2-3.f*y2);
  Y[24]=0.6258357354491761f*(x2*x2-6.f*x2*y2+y2*y2);
}

// ======================= CSR build =======================

__global__ __launch_bounds__(1024) void k_scan(const int* __restrict__ cnt, int* offs, int* cursor, int N){
  __shared__ int part[1024];
  int t=threadIdx.x;
  int per=(N+1023)>>10;
  int start=t*per;
  int s=0;
  for(int i2=0;i2<per;i2++){int idx=start+i2; if(idx<N) s+=cnt[idx];}
  part[t]=s; __syncthreads();
  for(int off=1;off<1024;off<<=1){
    int v=(t>=off)?part[t-off]:0;
    __syncthreads();
    part[t]+=v;
    __syncthreads();
  }
  int run=(t>0)?part[t-1]:0;
  for(int i2=0;i2<per;i2++){int idx=start+i2; if(idx<N){offs[idx]=run; cursor[idx]=run; run+=cnt[idx];}}
  if(t==1023) offs[N]=part[1023];
}

__global__ __launch_bounds__(256) void k_fill(const int* __restrict__ nbr, int* cursor, int* elist, int E){
  int e=blockIdx.x*256+threadIdx.x; if(e>=E)return;
  int pos=atomicAdd(&cursor[nbr[2*e]],1);
  elist[pos]=e;
}

// ======================= aggregation: y0 -> d_out ch 0..15 (p0 rows only, RAW) =============

__global__ __launch_bounds__(64) void k_agg(const float* __restrict__ g, const float* __restrict__ Ye,
    const int* __restrict__ offs, const int* __restrict__ elist, const float* __restrict__ norm,
    float* __restrict__ y){
  int n=blockIdx.x, t=threadIdx.x;
  __shared__ float gs[16];
  __shared__ float ys[25];
  float acc[7];
  #pragma unroll
  for(int i2=0;i2<7;i2++) acc[i2]=0.f;
  int e0=offs[n], e1=offs[n+1];
  for(int ei=e0; ei<e1; ei++){
    int e=elist[ei];
    if(t<16) gs[t]=g[(size_t)e*16+t];
    else if(t<41) ys[t-16]=Ye[(size_t)e*25+t-16];
    __syncthreads();
    #pragma unroll
    for(int i2=0;i2<7;i2++){
      int o=t+64*i2;
      if(o<400) acc[i2] += ys[o>>4]*gs[o&15];
    }
    __syncthreads();
  }
  float nv=1.0f/norm[0];
  float* yo=y+(size_t)n*7200;
  #pragma unroll
  for(int i2=0;i2<7;i2++){
    int o=t+64*i2;
    if(o<400){ int lm=o>>4,k=o&15; yo[lm*144+k]=acc[i2]*nv; }
  }
}

// ======================= te precompute: te[n][c] = emb[Z[n]] @ Wet + bet ==================

__global__ __launch_bounds__(128) void k_te(const int* __restrict__ Z, const float* __restrict__ emb,
    const float* __restrict__ Wet, const float* __restrict__ bet, float* __restrict__ te){
  int n=blockIdx.x, t=threadIdx.x;
  __shared__ float embs[64];
  int z=Z[n];
  if(t<64) embs[t]=emb[z*64+t];
  __syncthreads();
  for(int c=t;c<144;c+=128){
    float s=bet[c];
    for(int d=0;d<64;d++) s+=embs[d]*Wet[d*144+c];
    te[(size_t)n*144+c]=s;
  }
}

// ======================= TP0 — 1 wave/atom; act-writes ch0..15, raw ch16..79 ==============

__global__ __launch_bounds__(64) __attribute__((amdgpu_waves_per_eu(1,4)))
void k_tp0(float* __restrict__ y, const float* __restrict__ W1,
    const float* __restrict__ W2, const float* __restrict__ wp,
    const float* __restrict__ te, const float* __restrict__ wf){
  int n=blockIdx.x, f=threadIdx.x;
  float* ybase = y + (size_t)n*7200;

  // lane f holds ch (f&15), 4-way replicated (raw y0, p0 rows)
  float y0r[25];
  #pragma unroll
  for(int lm=0;lm<25;lm++) y0r[lm]=ybase[lm*144+(f&15)];

  // degree-dense (K=16)
  float a[25],b[25];
  #pragma unroll
  for(int i=0;i<25;i++){a[i]=0.f;b[i]=0.f;}
  #pragma unroll
  for(int l=0;l<5;l++){
    const int n1=2*l+1, base=l*l;
    const float* w1=W1+l*1024+f;
    const float* w2=W2+l*1024+f;
    #pragma unroll 8
    for(int k=0;k<16;k++){
      float u1=w1[k*64], u2=w2[k*64];
      #pragma unroll
      for(int j=0;j<n1;j++){
        float yv=rl(y0r[base+j],k);
        a[base+j]+=yv*u1; b[base+j]+=yv*u2;
      }
    }
  }

  // fused final for ch 0..15 (y0r consumed; p1 rows are act(0)=0)
  {
    float te0=te[(size_t)n*144+(f&15)];
    #pragma unroll
    for(int lm=0;lm<25;lm++){
      float wv=wf[lof_(lm)*144+(f&15)];    // p=0 block
      float v=te0*y0r[lm]*wv;
      if(lm==0) v+=te0;
      v=actv(v);
      if(f<16){
        ybase[lm*144+f]=v;
        ybase[(25+lm)*144+f]=0.f;
      }
    }
  }

  // CG -> RAW store ch 16..79
  float* yo=ybase+16;
  t0_l3<0>(typename mkseq<65>::type{}, a,b,wp,f,yo);
  t0_l3<1>(typename mkseq<65>::type{}, a,b,wp,f,yo);
  t0_l3<2>(typename mkseq<65>::type{}, a,b,wp,f,yo);
  t0_l3<3>(typename mkseq<65>::type{}, a,b,wp,f,yo);
  t0_l3<4>(typename mkseq<65>::type{}, a,b,wp,f,yo);
}

// ======================= TP1 — 1 wave/atom; act-rewrites ch16..79, act-writes ch80..143 ===

__global__ __launch_bounds__(64) __attribute__((amdgpu_waves_per_eu(1,3)))
void k_tp1(float* __restrict__ y, const float* __restrict__ W1,
    const float* __restrict__ W2, const float* __restrict__ wp,
    const float* __restrict__ te, const float* __restrict__ wf){
  int n=blockIdx.x, f=threadIdx.x;
  float* ybase = y + (size_t)n*7200;
  const float* yin = ybase + 16;
  float te1=te[(size_t)n*144+16+f];
  float a0[25],a1[25],b0[25],b1[25];
  #pragma unroll
  for(int i=0;i<25;i++){a0[i]=0.f;a1[i]=0.f;b0[i]=0.f;b1[i]=0.f;}
  #pragma unroll
  for(int p=0;p<2;p++){
    #pragma unroll
    for(int l=0;l<5;l++){
      const int n1=2*l+1, base=l*l;
      float yk[9];
      #pragma unroll
      for(int j=0;j<n1;j++) yk[j]=yin[p*3600+(base+j)*144+f];   // raw y1, lane=ch 16+f
      const float* w1=W1+(p*5+l)*4096+f;
      const float* w2=W2+(p*5+l)*4096+f;
      #pragma unroll 8
      for(int k=0;k<64;k++){
        float u1=w1[k*64], u2=w2[k*64];
        #pragma unroll
        for(int j=0;j<n1;j++){
          float yv=rl(yk[j],k);
          if(p==0){ a0[base+j]+=yv*u1; b0[base+j]+=yv*u2; }
          else    { a1[base+j]+=yv*u1; b1[base+j]+=yv*u2; }
        }
      }
      // fused final for these rows of ch 16..79 (yk raw still in regs)
      float wv=wf[(p*5+l)*144+16+f];
      #pragma unroll
      for(int j=0;j<n1;j++){
        float v=te1*yk[j]*wv;
        if(p==0&&l==0&&j==0) v+=te1;
        v=actv(v);
        ybase[(p*25+base+j)*144+16+f]=v;
      }
    }
  }
  // CG + fused final, ch 80..143
  float te2=te[(size_t)n*144+80+f];
  t1_l3w<0>(typename mkseq<65>::type{}, a0,a1,b0,b1,wp,f,ybase,wf,te2);
  t1_l3w<1>(typename mkseq<65>::type{}, a0,a1,b0,b1,wp,f,ybase,wf,te2);
  t1_l3w<2>(typename mkseq<65>::type{}, a0,a1,b0,b1,wp,f,ybase,wf,te2);
  t1_l3w<3>(typename mkseq<65>::type{}, a0,a1,b0,b1,wp,f,ybase,wf,te2);
  t1_l3w<4>(typename mkseq<65>::type{}, a0,a1,b0,b1,wp,f,ybase,wf,te2);
}

// ======================= launch =======================

extern "C" void kernel_launch(void* const* d_in, const int* in_sizes, int n_in,
                              void* d_out, int out_size, void* d_ws, size_t ws_size,
                              hipStream_t stream) {
  const int*   Z    =(const int*)  d_in[0];
  const int*   nbr  =(const int*)  d_in[1];
  const float* disp =(const float*)d_in[2];
  const float* Wsp  =(const float*)d_in[3];
  const float* emb  =(const float*)d_in[4];
  const float* Wet  =(const float*)d_in[5];
  const float* bet  =(const float*)d_in[6];
  const float* norm =(const float*)d_in[7];
  const float* t0W1 =(const float*)d_in[8];
  const float* t0W2 =(const float*)d_in[9];
  const float* t0wp =(const float*)d_in[10];
  const float* t1W1 =(const float*)d_in[11];
  const float* t1W2 =(const float*)d_in[12];
  const float* t1wp =(const float*)d_in[13];
  const float* wf   =(const float*)d_in[14];
  int N=in_sizes[0];
  int E=in_sizes[1]/2;
  float* y=(float*)d_out;

  char* w=(char*)d_ws;
  size_t off=0;
  auto take=[&](size_t bytes)->void*{ size_t cur=(off+255)&~(size_t)255; off=cur+bytes; return (void*)(w+cur); };
  int*   cnt   =(int*)  take((size_t)N*4);
  int*   offs  =(int*)  take((size_t)(N+1)*4);
  int*   cursor=(int*)  take((size_t)N*4);
  int*   elist =(int*)  take((size_t)E*4);
  float* g     =(float*)take((size_t)E*16*4);
  float* Ye    =(float*)take((size_t)E*25*4);
  float* te    =(float*)take((size_t)N*144*4);
  (void)ws_size; (void)out_size; (void)n_in;

  k_zero   <<<dim3((N+255)/256),   dim3(256), 0, stream>>>(cnt, N);
  k_edge   <<<dim3((E+255)/256),   dim3(256), 0, stream>>>(Z, nbr, disp, Wsp, g, Ye, cnt, E);
  k_scan   <<<dim3(1),             dim3(1024),0, stream>>>(cnt, offs, cursor, N);
  k_fill   <<<dim3((E+255)/256),   dim3(256), 0, stream>>>(nbr, cursor, elist, E);
  k_agg    <<<dim3(N),             dim3(64),  0, stream>>>(g, Ye, offs, elist, norm, y);
  k_te     <<<dim3(N),             dim3(128), 0, stream>>>(Z, emb, Wet, bet, te);
  k_tp0    <<<dim3(N),             dim3(64),  0, stream>>>(y, t0W1, t0W2, t0wp, te, wf);
  k_tp1    <<<dim3(N),             dim3(64),  0, stream>>>(y, t1W1, t1W2, t1wp, te, wf);
}